// Round 4
// baseline (272.349 us; speedup 1.0000x reference)
//
#include <hip/hip_runtime.h>
#include <math.h>

// ROI-Align over FPN levels p2..p5 (NHWC, C=256), 7x7 pool, output permuted
// by stable argsort of roi_level.
//
// SINGLE fused kernel. Each block redundantly computes the per-ROI level +
// stable-sort scatter position (ballot ranks over 64-wide chunks + tiny
// serial scan, ~1-2 us, amortized over 96 tasks/block) for the <=3 ROIs its
// tasks touch. Removes the serial 1-block setup launch + dependency and
// turns per-task level/pos/roi loads into LDS broadcasts.
//
// Hardening vs previous submission: no vector-type casts of input pointers
// (scalar rois loads only), explicit r<R guards everywhere.

#define MAX_R 2048   // R = B*N = 2000 in this problem
#define NCHUNK_MAX (MAX_R / 64)

typedef float f32x4 __attribute__((ext_vector_type(4)));

#define TASKS_PER_WAVE 4
#define WAVES_PER_BLOCK 4
#define BLOCK_ITERS 6
#define TASKS_PER_BLOCK (TASKS_PER_WAVE * WAVES_PER_BLOCK * BLOCK_ITERS)  // 96

struct BinTask {
    const f32x4* f4;
    unsigned i00, i01, i10, i11, oidx;   // 32-bit float4-element indices
    float wx, wy, vmask;
};

__device__ __forceinline__ int roi_level_f(float y1, float x1, float y2, float x2,
                                           float canon) {
    const float hw = (y2 - y1) * (x2 - x1);
    const float s = sqrtf(fmaxf(hw, 1e-12f));
    const float spec = log2f(s / canon);
    float rf = rintf(spec);                    // round-half-to-even
    // guard: if within 1e-4 of a .5 boundary, redo in double (matches ref)
    if (fabsf(fabsf(spec - rf) - 0.5f) < 1e-4f) {
        rf = (float)rint(log2((double)s / (double)canon));
    }
    int l = 4 + (int)rf;
    return min(5, max(2, l)) - 2;              // 0..3
}

__device__ __forceinline__ BinTask make_task(int work, int N, int rlo,
        const int* lvl_loc, const int* pos_loc, const float* roi_loc,
        const float* __restrict__ p2, const float* __restrict__ p3,
        const float* __restrict__ p4, const float* __restrict__ p5,
        int lane) {
    BinTask T;
    const int r   = work / 49;
    const int bin = work - r * 49;
    const int py  = bin / 7;
    const int px  = bin - py * 7;
    const int b   = (int)((unsigned)r / (unsigned)N);

    const int k = r - rlo;          // 0..2 (96 tasks span <=3 ROIs)
    const int l = lvl_loc[k];
    const float y1 = roi_loc[k * 4 + 0];
    const float x1 = roi_loc[k * 4 + 1];
    const float y2 = roi_loc[k * 4 + 2];
    const float x2 = roi_loc[k * 4 + 3];

    const float* feat;
    int H;
    switch (l) {
        case 0:  feat = p2; H = 256; break;
        case 1:  feat = p3; H = 128; break;
        case 2:  feat = p4; H = 64;  break;
        default: feat = p5; H = 32;  break;
    }
    const int W = H;

    // match reference op order: (y1 + fy*(y2-y1)) * (H-1), fy = py/6
    const float fy = (float)py / 6.0f;
    const float fx = (float)px / 6.0f;
    const float in_y = (y1 + fy * (y2 - y1)) * (float)(H - 1);
    const float in_x = (x1 + fx * (x2 - x1)) * (float)(W - 1);

    const float y0f = floorf(in_y);
    const float x0f = floorf(in_x);
    T.wy = in_y - y0f;
    T.wx = in_x - x0f;
    const int y0i = (int)y0f;
    const int x0i = (int)x0f;
    const int y0c = min(H - 1, max(0, y0i));
    const int y1c = min(H - 1, max(0, y0i + 1));
    const int x0c = min(W - 1, max(0, x0i));
    const int x1c = min(W - 1, max(0, x0i + 1));

    T.vmask = (in_y >= 0.0f && in_y <= (float)(H - 1) &&
               in_x >= 0.0f && in_x <= (float)(W - 1)) ? 1.0f : 0.0f;

    T.f4 = (const f32x4*)feat;
    const unsigned bb = (unsigned)b * (unsigned)(H * W * 64);
    T.i00 = bb + (unsigned)(y0c * W + x0c) * 64u + (unsigned)lane;
    T.i01 = bb + (unsigned)(y0c * W + x1c) * 64u + (unsigned)lane;
    T.i10 = bb + (unsigned)(y1c * W + x0c) * 64u + (unsigned)lane;
    T.i11 = bb + (unsigned)(y1c * W + x1c) * 64u + (unsigned)lane;
    T.oidx = ((unsigned)pos_loc[k] * 49u + (unsigned)bin) * 64u + (unsigned)lane;
    return T;
}

__device__ __forceinline__ f32x4 blend(f32x4 v00, f32x4 v01,
                                       f32x4 v10, f32x4 v11,
                                       float wx, float wy, float vmask) {
    const float omwx = 1.0f - wx;
    const float omwy = 1.0f - wy;
    const f32x4 top = v00 * omwx + v01 * wx;
    const f32x4 bot = v10 * omwx + v11 * wx;
    return (top * omwy + bot * wy) * vmask;
}

__global__ __launch_bounds__(256)
void roi_align_fused(const float* __restrict__ rois,
                     const int* __restrict__ image_h,
                     const int* __restrict__ image_w,
                     const float* __restrict__ p2,
                     const float* __restrict__ p3,
                     const float* __restrict__ p4,
                     const float* __restrict__ p5,
                     float* __restrict__ out,
                     int R, int N, int total) {
    __shared__ unsigned long long masks_sh[NCHUNK_MAX][4];
    __shared__ int cnt_sh[NCHUNK_MAX][4];
    __shared__ int base_sh[NCHUNK_MAX][4];
    __shared__ signed char lvl_sh[MAX_R];
    __shared__ int lvl_loc[4];
    __shared__ int pos_loc[4];
    __shared__ float roi_loc[4 * 4];

    const int t    = threadIdx.x;
    const int lane = t & 63;
    const int wv   = t >> 6;
    const int nchunk = (R + 63) / 64;

    const float canon = 224.0f / sqrtf((float)(image_h[0] * image_w[0]));

    // ---- Phase A: levels for ALL ROIs + per-chunk ballot masks ----
    for (int c = wv; c < nchunk; c += WAVES_PER_BLOCK) {
        const int r = c * 64 + lane;
        int l = -1;
        if (r < R) {
            const float y1 = rois[r * 4 + 0];
            const float x1 = rois[r * 4 + 1];
            const float y2 = rois[r * 4 + 2];
            const float x2 = rois[r * 4 + 3];
            l = roi_level_f(y1, x1, y2, x2, canon);
            lvl_sh[r] = (signed char)l;
        }
        unsigned long long m[4];
        #pragma unroll
        for (int i = 0; i < 4; ++i) m[i] = __ballot(l == i);
        if (lane < 4) {
            masks_sh[c][lane] = m[lane];
            cnt_sh[c][lane]   = __popcll(m[lane]);
        }
    }
    __syncthreads();

    // ---- Phase B: tiny serial scan (nchunk<=32 x 4 levels) ----
    if (t == 0) {
        int tot[4] = {0, 0, 0, 0};
        for (int c = 0; c < nchunk; ++c)
            for (int l = 0; l < 4; ++l) {
                base_sh[c][l] = tot[l];
                tot[l] += cnt_sh[c][l];
            }
        int base[4];
        int acc = 0;
        for (int l = 0; l < 4; ++l) { base[l] = acc; acc += tot[l]; }
        for (int c = 0; c < nchunk; ++c)
            for (int l = 0; l < 4; ++l) base_sh[c][l] += base[l];
    }
    __syncthreads();

    // ---- Phase C: level/pos/coords for this block's <=3 ROIs ----
    const int task_base = blockIdx.x * TASKS_PER_BLOCK;
    const int last = total - 1;
    const int rlo = task_base / 49;
    const int rhi = min(last, task_base + TASKS_PER_BLOCK - 1) / 49;
    if (t <= rhi - rlo) {
        const int r = rlo + t;
        if (r < R) {
            const int l = lvl_sh[r];
            const int c = r >> 6;
            const unsigned long long below = (1ull << (r & 63)) - 1ull;
            lvl_loc[t] = l;
            pos_loc[t] = base_sh[c][l] + __popcll(masks_sh[c][l] & below);
            roi_loc[t * 4 + 0] = rois[r * 4 + 0];
            roi_loc[t * 4 + 1] = rois[r * 4 + 1];
            roi_loc[t * 4 + 2] = rois[r * 4 + 2];
            roi_loc[t * 4 + 3] = rois[r * 4 + 3];
        }
    }
    __syncthreads();

    // ---- Main loop: 6 iters x 4 waves x 4 tasks = 96 tasks/block ----
    f32x4* __restrict__ o4 = (f32x4*)out;

    for (int it = 0; it < BLOCK_ITERS; ++it) {
        const int t0 = task_base + it * (TASKS_PER_WAVE * WAVES_PER_BLOCK)
                     + wv * TASKS_PER_WAVE;
        if (t0 > last) break;

        BinTask T0 = make_task(min(t0 + 0, last), N, rlo, lvl_loc, pos_loc, roi_loc, p2, p3, p4, p5, lane);
        BinTask T1 = make_task(min(t0 + 1, last), N, rlo, lvl_loc, pos_loc, roi_loc, p2, p3, p4, p5, lane);
        BinTask T2 = make_task(min(t0 + 2, last), N, rlo, lvl_loc, pos_loc, roi_loc, p2, p3, p4, p5, lane);
        BinTask T3 = make_task(min(t0 + 3, last), N, rlo, lvl_loc, pos_loc, roi_loc, p2, p3, p4, p5, lane);

        // issue all 16 loads before any use (16 outstanding 1 KB transactions)
        const f32x4 a00 = T0.f4[T0.i00];
        const f32x4 a01 = T0.f4[T0.i01];
        const f32x4 a10 = T0.f4[T0.i10];
        const f32x4 a11 = T0.f4[T0.i11];
        const f32x4 b00 = T1.f4[T1.i00];
        const f32x4 b01 = T1.f4[T1.i01];
        const f32x4 b10 = T1.f4[T1.i10];
        const f32x4 b11 = T1.f4[T1.i11];
        const f32x4 c00 = T2.f4[T2.i00];
        const f32x4 c01 = T2.f4[T2.i01];
        const f32x4 c10 = T2.f4[T2.i10];
        const f32x4 c11 = T2.f4[T2.i11];
        const f32x4 d00 = T3.f4[T3.i00];
        const f32x4 d01 = T3.f4[T3.i01];
        const f32x4 d10 = T3.f4[T3.i10];
        const f32x4 d11 = T3.f4[T3.i11];

        o4[T0.oidx] = blend(a00, a01, a10, a11, T0.wx, T0.wy, T0.vmask);
        if (t0 + 1 <= last)
            o4[T1.oidx] = blend(b00, b01, b10, b11, T1.wx, T1.wy, T1.vmask);
        if (t0 + 2 <= last)
            o4[T2.oidx] = blend(c00, c01, c10, c11, T2.wx, T2.wy, T2.vmask);
        if (t0 + 3 <= last)
            o4[T3.oidx] = blend(d00, d01, d10, d11, T3.wx, T3.wy, T3.vmask);
    }
}

extern "C" void kernel_launch(void* const* d_in, const int* in_sizes, int n_in,
                              void* d_out, int out_size, void* d_ws, size_t ws_size,
                              hipStream_t stream) {
    const float* rois = (const float*)d_in[0];
    const int*   ih   = (const int*)d_in[1];
    const int*   iw   = (const int*)d_in[2];
    const float* p2   = (const float*)d_in[3];
    const float* p3   = (const float*)d_in[4];
    const float* p4   = (const float*)d_in[5];
    const float* p5   = (const float*)d_in[6];

    const int R = in_sizes[0] / 4;                       // B*N
    const int B = in_sizes[3] / (256 * 256 * 256);       // p2 is (B,256,256,256)
    const int N = R / B;
    const int total = R * 49;

    const int blocks = (total + TASKS_PER_BLOCK - 1) / TASKS_PER_BLOCK;  // 1021
    roi_align_fused<<<blocks, 256, 0, stream>>>(rois, ih, iw, p2, p3, p4, p5,
                                                (float*)d_out, R, N, total);
}

// Round 5
// 265.330 us; speedup vs baseline: 1.0265x; 1.0265x over previous
//
#include <hip/hip_runtime.h>
#include <math.h>

// ROI-Align over FPN levels p2..p5 (NHWC, C=256), 7x7 pool, output permuted
// by stable argsort of roi_level.
//
// Kernel 1 (setup): per-ROI level + stable scatter position. Parallel:
// ballot-based within-chunk rank (64-wide chunks) + tiny serial chunk scan.
// Kernel 2 (main): grid-stride persistent waves, 2 bins per wave-iteration
// (8 outstanding 1 KB loads) for memory-level parallelism.
//
// This is the best-measured configuration (265.2 us). Variants tried and
// rejected (all neutral-to-worse, within/below noise):
//  - nt-stores + 4 tasks/wave + block-contiguous chunks: 269.6 us
//  - single fused kernel (per-block redundant setup):     272.3 us
// Main kernel sits ~1.3x above its traffic floor (output 100 MB + touched
// feature footprint; feature maps fully L3-resident at 178 MB); the rest of
// dur_us is fixed harness re-poison fills (~82 us each, 80% HBM peak).

#define MAX_R 2048   // R = B*N = 2000 in this problem
#define NCHUNK_MAX (MAX_R / 64)

__global__ __launch_bounds__(1024)
void roi_setup_kernel(const float* __restrict__ rois,
                      const int* __restrict__ image_h,
                      const int* __restrict__ image_w,
                      int R,
                      int* __restrict__ level_out,
                      int* __restrict__ pos_out) {
    __shared__ int lvl_sh[MAX_R];
    __shared__ int wrank_sh[MAX_R];
    __shared__ int chunk_cnt[NCHUNK_MAX][4];
    __shared__ int chunk_base[NCHUNK_MAX][4];

    const int t    = threadIdx.x;
    const int lane = t & 63;
    const int wave = t >> 6;
    const int nwaves = blockDim.x >> 6;
    const int nchunk = (R + 63) / 64;

    const float canon = 224.0f / sqrtf((float)(image_h[0] * image_w[0]));

    // Phase 1+2: level + within-chunk stable rank via ballot
    for (int c = wave; c < nchunk; c += nwaves) {
        const int r = c * 64 + lane;
        int l = -1;
        if (r < R) {
            const float y1 = rois[r * 4 + 0];
            const float x1 = rois[r * 4 + 1];
            const float y2 = rois[r * 4 + 2];
            const float x2 = rois[r * 4 + 3];
            const float hw = (y2 - y1) * (x2 - x1);
            const float s = sqrtf(fmaxf(hw, 1e-12f));
            // double log2 + rint: round-half-to-even, matching jnp.round
            const double spec = log2((double)s / (double)canon);
            l = 4 + (int)rint(spec);
            l = min(5, max(2, l)) - 2;   // 0..3
            lvl_sh[r] = l;
        }
        unsigned long long m[4];
        #pragma unroll
        for (int i = 0; i < 4; ++i) m[i] = __ballot(l == i);
        if (r < R) {
            const unsigned long long below = (1ull << lane) - 1ull;
            wrank_sh[r] = __popcll(m[l] & below);
        }
        if (lane < 4) chunk_cnt[c][lane] = __popcll(m[lane]);
    }
    __syncthreads();

    // Phase 3: tiny serial scan (nchunk<=32, 4 levels)
    if (t == 0) {
        int tot[4] = {0, 0, 0, 0};
        for (int c = 0; c < nchunk; ++c)
            for (int l = 0; l < 4; ++l) {
                chunk_base[c][l] = tot[l];
                tot[l] += chunk_cnt[c][l];
            }
        int base[4];
        int acc = 0;
        for (int l = 0; l < 4; ++l) { base[l] = acc; acc += tot[l]; }
        for (int c = 0; c < nchunk; ++c)
            for (int l = 0; l < 4; ++l) chunk_base[c][l] += base[l];
    }
    __syncthreads();

    // Phase 4: scatter positions
    for (int r = t; r < R; r += blockDim.x) {
        const int l = lvl_sh[r];
        level_out[r] = l;
        pos_out[r] = chunk_base[r >> 6][l] + wrank_sh[r];
    }
}

struct BinTask {
    const float4* f4;
    size_t i00, i01, i10, i11, oidx;
    float wx, wy, vmask;
};

__device__ __forceinline__ BinTask make_task(int work, int N,
        const float* __restrict__ rois,
        const int* __restrict__ level,
        const int* __restrict__ pos,
        const float* __restrict__ p2, const float* __restrict__ p3,
        const float* __restrict__ p4, const float* __restrict__ p5,
        int lane) {
    BinTask T;
    const int r   = work / 49;
    const int bin = work % 49;
    const int py  = bin / 7;
    const int px  = bin % 7;
    const int b   = r / N;

    const int l = level[r];
    const float* feat;
    int H;
    switch (l) {
        case 0:  feat = p2; H = 256; break;
        case 1:  feat = p3; H = 128; break;
        case 2:  feat = p4; H = 64;  break;
        default: feat = p5; H = 32;  break;
    }
    const int W = H;

    const float y1 = rois[r * 4 + 0];
    const float x1 = rois[r * 4 + 1];
    const float y2 = rois[r * 4 + 2];
    const float x2 = rois[r * 4 + 3];

    // match reference op order: (y1 + fy*(y2-y1)) * (H-1), fy = py/6
    const float fy = (float)py / 6.0f;
    const float fx = (float)px / 6.0f;
    const float in_y = (y1 + fy * (y2 - y1)) * (float)(H - 1);
    const float in_x = (x1 + fx * (x2 - x1)) * (float)(W - 1);

    const float y0f = floorf(in_y);
    const float x0f = floorf(in_x);
    T.wy = in_y - y0f;
    T.wx = in_x - x0f;
    const int y0i = (int)y0f;
    const int x0i = (int)x0f;
    const int y0c = min(H - 1, max(0, y0i));
    const int y1c = min(H - 1, max(0, y0i + 1));
    const int x0c = min(W - 1, max(0, x0i));
    const int x1c = min(W - 1, max(0, x0i + 1));

    T.vmask = (in_y >= 0.0f && in_y <= (float)(H - 1) &&
               in_x >= 0.0f && in_x <= (float)(W - 1)) ? 1.0f : 0.0f;

    T.f4 = (const float4*)feat;
    const size_t bb = (size_t)b * H * W * 64;
    T.i00 = bb + ((size_t)y0c * W + x0c) * 64 + lane;
    T.i01 = bb + ((size_t)y0c * W + x1c) * 64 + lane;
    T.i10 = bb + ((size_t)y1c * W + x0c) * 64 + lane;
    T.i11 = bb + ((size_t)y1c * W + x1c) * 64 + lane;
    T.oidx = ((size_t)pos[r] * 49 + bin) * 64 + lane;
    return T;
}

__device__ __forceinline__ float4 blend(float4 v00, float4 v01,
                                        float4 v10, float4 v11,
                                        float wx, float wy, float vmask) {
    const float omwx = 1.0f - wx;
    const float omwy = 1.0f - wy;
    float4 res;
    res.x = ((v00.x * omwx + v01.x * wx) * omwy + (v10.x * omwx + v11.x * wx) * wy) * vmask;
    res.y = ((v00.y * omwx + v01.y * wx) * omwy + (v10.y * omwx + v11.y * wx) * wy) * vmask;
    res.z = ((v00.z * omwx + v01.z * wx) * omwy + (v10.z * omwx + v11.z * wx) * wy) * vmask;
    res.w = ((v00.w * omwx + v01.w * wx) * omwy + (v10.w * omwx + v11.w * wx) * wy) * vmask;
    return res;
}

__global__ __launch_bounds__(256)
void roi_align_kernel(const float* __restrict__ rois,
                      const float* __restrict__ p2,
                      const float* __restrict__ p3,
                      const float* __restrict__ p4,
                      const float* __restrict__ p5,
                      const int* __restrict__ level,
                      const int* __restrict__ pos,
                      float* __restrict__ out,
                      int N, int total) {
    const int lane   = threadIdx.x & 63;
    const int wave   = blockIdx.x * (blockDim.x >> 6) + (threadIdx.x >> 6);
    const int nwaves = gridDim.x * (blockDim.x >> 6);
    float4* __restrict__ o4 = (float4*)out;

    for (int w0 = wave * 2; w0 < total; w0 += nwaves * 2) {
        const bool hasB = (w0 + 1) < total;
        BinTask A = make_task(w0, N, rois, level, pos, p2, p3, p4, p5, lane);
        BinTask B = make_task(hasB ? w0 + 1 : w0, N, rois, level, pos, p2, p3, p4, p5, lane);

        // issue all 8 loads before any use
        const float4 a00 = A.f4[A.i00];
        const float4 a01 = A.f4[A.i01];
        const float4 a10 = A.f4[A.i10];
        const float4 a11 = A.f4[A.i11];
        const float4 b00 = B.f4[B.i00];
        const float4 b01 = B.f4[B.i01];
        const float4 b10 = B.f4[B.i10];
        const float4 b11 = B.f4[B.i11];

        o4[A.oidx] = blend(a00, a01, a10, a11, A.wx, A.wy, A.vmask);
        if (hasB)
            o4[B.oidx] = blend(b00, b01, b10, b11, B.wx, B.wy, B.vmask);
    }
}

extern "C" void kernel_launch(void* const* d_in, const int* in_sizes, int n_in,
                              void* d_out, int out_size, void* d_ws, size_t ws_size,
                              hipStream_t stream) {
    const float* rois = (const float*)d_in[0];
    const int*   ih   = (const int*)d_in[1];
    const int*   iw   = (const int*)d_in[2];
    const float* p2   = (const float*)d_in[3];
    const float* p3   = (const float*)d_in[4];
    const float* p4   = (const float*)d_in[5];
    const float* p5   = (const float*)d_in[6];

    const int R = in_sizes[0] / 4;                       // B*N
    const int B = in_sizes[3] / (256 * 256 * 256);       // p2 is (B,256,256,256)
    const int N = R / B;
    const int total = R * 49;

    int* level = (int*)d_ws;
    int* pos   = level + R;

    roi_setup_kernel<<<1, 1024, 0, stream>>>(rois, ih, iw, R, level, pos);
    // 2048 blocks x 4 waves = 8192 waves; 2 bins/wave-iter -> ~6 iters/wave
    roi_align_kernel<<<2048, 256, 0, stream>>>(rois, p2, p3, p4, p5,
                                               level, pos, (float*)d_out, N, total);
}